// Round 10
// baseline (574.595 us; speedup 1.0000x reference)
//
#include <hip/hip_runtime.h>
#include <hip/hip_fp16.h>

typedef _Float16 half8 __attribute__((ext_vector_type(8)));
typedef float f32x4 __attribute__((ext_vector_type(4)));

#define BATCH 65536
#define M1 196608   // 3*BATCH
#define K1 160      // X cols permuted: [nodes(128)|act(4)|body(10)|obj(15)|pad(3)]

// global -> LDS direct, 16B per lane, dest = wave-uniform base + lane*16
#define GLL16(g, l) __builtin_amdgcn_global_load_lds( \
    (const __attribute__((address_space(1))) unsigned int*)(const void*)(g), \
    (__attribute__((address_space(3))) unsigned int*)(void*)(l), 16, 0, 0)

// ---------------- prep: weights -> fp16 n-major k-contig (permuted/padded), merged biases ----------------
// W1t[512][160], W2t[2][512][256], R1t[2][256][512]
__global__ void prep_kernel(const float* __restrict__ p1w1, const float* __restrict__ p2w1,
                            const float* __restrict__ p1w2, const float* __restrict__ p2w2,
                            const float* __restrict__ r1w1, const float* __restrict__ r2w1,
                            const float* __restrict__ p1b1, const float* __restrict__ p2b1,
                            const float* __restrict__ p1b2, const float* __restrict__ p2b2,
                            const float* __restrict__ rb1a, const float* __restrict__ rb1b,
                            _Float16* __restrict__ W1t, _Float16* __restrict__ W2t,
                            _Float16* __restrict__ R1t, float* __restrict__ b1cat,
                            float* __restrict__ b2cat, float* __restrict__ rbias) {
    int e = blockIdx.x * 256 + threadIdx.x;
    if (e < 81920) {  // W1t[512][160]
        int n = e / 160, c = e % 160;
        int k = (c < 128) ? (29 + c) : (c - 128);   // col order: nodes | act,body,obj | pad
        float v = 0.f;
        if (c < 157) v = (n < 256) ? p1w1[k * 256 + n] : p2w1[k * 256 + (n - 256)];
        W1t[e] = (_Float16)v;
        return;
    }
    e -= 81920;
    if (e < 262144) {  // W2t[2][512][256]
        int net = e >> 17, rr = e & 131071;
        int n = rr >> 8, k = rr & 255;
        const float* w = net ? p2w2 : p1w2;
        W2t[(size_t)net * 131072 + rr] = (n < 471) ? (_Float16)w[k * 471 + n] : (_Float16)0.f;
        return;
    }
    e -= 262144;
    if (e < 262144) {  // R1t[2][256][512]
        int net = e >> 17, rr = e & 131071;
        int n = rr >> 9, k = rr & 511;
        const float* w = net ? r2w1 : r1w1;
        R1t[(size_t)net * 131072 + rr] = (k < 471) ? (_Float16)w[k * 256 + n] : (_Float16)0.f;
        return;
    }
    e -= 262144;
    if (e < 512) { b1cat[e] = (e < 256) ? p1b1[e] : p2b1[e - 256]; return; }
    e -= 512;
    if (e < 1024) {
        int net = e >> 9, n = e & 511;
        b2cat[e] = (n < 471) ? (net ? p2b2 : p1b2)[n] : 0.f;
        return;
    }
    e -= 1024;
    if (e < 512) {
        int net = e >> 8, n = e & 255;
        rbias[e] = (net ? rb1b : rb1a)[n];
    }
}

// ---------------- build X (3B x 160) fp16, permuted cols: [nodes|act|body|obj|pad] ----------------
__global__ void build_x(const float* __restrict__ obs, const float* __restrict__ act,
                        const float* __restrict__ nodes, _Float16* __restrict__ Xh) {
    long idx = (long)blockIdx.x * 256 + threadIdx.x;   // one 16B chunk each; 196608*20 total
    int ch = (int)(idx % 20);
    long r = idx / 20;
    int o = (int)(r >> 16), b = (int)(r & 65535);
    half8 v;
    if (ch < 16) {
        const float* s = nodes + r * 128 + ch * 8;
#pragma unroll
        for (int j = 0; j < 8; ++j) v[j] = (_Float16)s[j];
    } else {
#pragma unroll
        for (int j = 0; j < 8; ++j) {
            int lc = ch * 8 + j - 128;
            float f = 0.f;
            if (lc < 4)       f = act[b * 4 + lc];
            else if (lc < 14) f = obs[b * 55 + (lc - 4)];
            else if (lc < 29) f = obs[b * 55 + 10 + o * 15 + (lc - 14)];
            v[j] = (_Float16)f;
        }
    }
    *(half8*)(Xh + r * K1 + ch * 8) = v;
}

// ---------------- gemm1: H[net][3B][256] = relu(X @ W1 + b1), K=160, BK=32 (5 rounds) ----------------
// 4 waves 64x64, LDS 32 KB, 2-phase dbuf (R9-proven)
__global__ __launch_bounds__(256) void gemm1(const _Float16* __restrict__ Xh,
                                             const _Float16* __restrict__ W1t,
                                             const float* __restrict__ b1cat,
                                             _Float16* __restrict__ H) {
    __shared__ _Float16 As[2][4096];    // 128 x 32
    __shared__ _Float16 Bs[2][4096];
    const int tid = threadIdx.x;
    int bid = blockIdx.x;                       // 6144 = 8 XCD x 768, n fastest (4 siblings share A)
    int w = (bid & 7) * 768 + (bid >> 3);
    const int m0 = (w >> 2) * 128, n0 = (w & 3) * 128;
    const _Float16* Ab = Xh + (long)m0 * K1;
    const _Float16* Bb = W1t + (long)n0 * K1;
    const int wid = tid >> 6, lane = tid & 63;
    const int lm = lane & 15, lq = lane >> 4;
    const int wr = (wid >> 1) * 64, wc = (wid & 1) * 64;

    auto stage = [&](int s, int buf) {          // BK=32: 2+2 GLL16/thread; dest = c*8 halves
        int ko = s * 32;
#pragma unroll
        for (int t = 0; t < 2; ++t) {
            int c = t * 256 + tid, row = c >> 2, chk = c & 3;
            int q = chk ^ ((row >> 1) & 3);
            GLL16(Ab + (long)row * K1 + ko + q * 8, &As[buf][0] + t * 2048 + wid * 512);
            GLL16(Bb + (long)row * K1 + ko + q * 8, &Bs[buf][0] + t * 2048 + wid * 512);
        }
    };

    stage(0, 0);
    __syncthreads();

    const int cc = (lq ^ ((lm >> 1) & 3)) * 8;
    f32x4 acc[4][4] = {};
    int cur = 0;
#pragma unroll
    for (int r = 0; r < 5; ++r) {
        if (r < 4) stage(r + 1, cur ^ 1);
        const _Float16* ab = &As[cur][0];
        const _Float16* bb = &Bs[cur][0];
        half8 a[4], b[4];
#pragma unroll
        for (int i = 0; i < 4; ++i) a[i] = *(const half8*)(ab + (wr + i * 16 + lm) * 32 + cc);
#pragma unroll
        for (int j = 0; j < 4; ++j) b[j] = *(const half8*)(bb + (wc + j * 16 + lm) * 32 + cc);
#pragma unroll
        for (int i = 0; i < 4; ++i)
#pragma unroll
            for (int j = 0; j < 4; ++j)
                acc[i][j] = __builtin_amdgcn_mfma_f32_16x16x32_f16(a[i], b[j], acc[i][j], 0, 0, 0);
        __syncthreads();
        cur ^= 1;
    }
#pragma unroll
    for (int j = 0; j < 4; ++j) {
        int n = n0 + wc + j * 16 + lm;
        int net = n >> 8, ncol = n & 255;
        float bi = b1cat[n];
        _Float16* hp = H + (long)net * ((long)M1 * 256) + ncol;
#pragma unroll
        for (int i = 0; i < 4; ++i) {
            int mrow = m0 + wr + i * 16 + lq * 4;
#pragma unroll
            for (int rg = 0; rg < 4; ++rg) {
                float v = acc[i][j][rg] + bi;
                v = v > 0.f ? v : 0.f;
                hp[(long)(mrow + rg) * 256] = (_Float16)v;
            }
        }
    }
}

// ---------------- gemm2 FLAT: Osum[net][B][512] = sum_o relu(H[net][o] @ W2^T + b2) ----------------
// No LDS, no barriers. B-fragments (32n x 256k per wave) resident in registers;
// A-fragments loaded directly from global (L1-deduped across 4 n-sibling waves).
// Block = 4 waves x 32n = 64m x 128n. Fully unrolled 3 obj x 8 k-steps.
__global__ __launch_bounds__(256) void gemm_sum_flat(const _Float16* __restrict__ H,
                                                     const _Float16* __restrict__ W2t,
                                                     const float* __restrict__ b2cat,
                                                     _Float16* __restrict__ Osum) {
    const int tid = threadIdx.x;
    int bid = blockIdx.x;                       // 8192 = 8 XCD x 1024; nq fastest, then net, then mt
    int w = (bid & 7) * 1024 + (bid >> 3);
    const int nq = w & 3, net = (w >> 2) & 1, mt = w >> 3;   // mt 0..1023 (64-row tiles)
    const int wid = tid >> 6, lane = tid & 63;
    const int lm = lane & 15, lq = lane >> 4;
    const int wc = wid * 32, n0 = nq * 128;

    // B fragments in registers: breg[j][s] = W2[n0+wc+j*16+lm][s*32+lq*8 ..+8]
    const _Float16* Wb = W2t + (long)net * 131072;
    half8 breg[2][8];
#pragma unroll
    for (int j = 0; j < 2; ++j) {
        const _Float16* wp = Wb + (long)(n0 + wc + j * 16 + lm) * 256 + lq * 8;
#pragma unroll
        for (int s = 0; s < 8; ++s)
            breg[j][s] = *(const half8*)(wp + s * 32);
    }
    float bi[2];
#pragma unroll
    for (int j = 0; j < 2; ++j) bi[j] = b2cat[net * 512 + n0 + wc + j * 16 + lm];

    f32x4 sum[4][2] = {};
    const long rowbase = (long)net * M1 + (long)mt * 64;
#pragma unroll
    for (int obj = 0; obj < 3; ++obj) {
        const _Float16* Ab = H + (rowbase + (long)obj * BATCH + lm) * 256 + lq * 8;
        f32x4 acc[4][2] = {};
#pragma unroll
        for (int s = 0; s < 8; ++s) {
            half8 a[4];
#pragma unroll
            for (int i = 0; i < 4; ++i)
                a[i] = *(const half8*)(Ab + (long)i * 4096 + s * 32);
#pragma unroll
            for (int i = 0; i < 4; ++i)
#pragma unroll
                for (int j = 0; j < 2; ++j)
                    acc[i][j] = __builtin_amdgcn_mfma_f32_16x16x32_f16(a[i], breg[j][s], acc[i][j], 0, 0, 0);
        }
#pragma unroll
        for (int i = 0; i < 4; ++i)
#pragma unroll
            for (int j = 0; j < 2; ++j)
#pragma unroll
                for (int rg = 0; rg < 4; ++rg) {
                    float v = acc[i][j][rg] + bi[j];
                    sum[i][j][rg] += (v > 0.f ? v : 0.f);
                }
    }
    _Float16* op = Osum + (long)net * ((long)BATCH * 512);
#pragma unroll
    for (int j = 0; j < 2; ++j) {
        int n = n0 + wc + j * 16 + lm;
#pragma unroll
        for (int i = 0; i < 4; ++i) {
            int mrow = mt * 64 + i * 16 + lq * 4;
#pragma unroll
            for (int rg = 0; rg < 4; ++rg)
                op[(long)(mrow + rg) * 512 + n] = (_Float16)sum[i][j][rg];
        }
    }
}

// ---------------- gemm3+qdot fused (R3-proven): q = relu(Osum @ R1 + rb1) . w2 + b2 ----------------
// BM=128, BN=256 (full per net), BK=64, 8 waves (64x64), K=512 -> 8 rounds, 2-phase dbuf
__global__ __launch_bounds__(512) void gemm3q(const _Float16* __restrict__ Osum,
                                              const _Float16* __restrict__ R1t,
                                              const float* __restrict__ rbias,
                                              const float* __restrict__ r1w2,
                                              const float* __restrict__ r2w2,
                                              const float* __restrict__ r1b2,
                                              const float* __restrict__ r2b2,
                                              float* __restrict__ out) {
    __shared__ _Float16 As[2][8192];
    __shared__ _Float16 Bs[2][16384];
    __shared__ float qlds[128];
    const int tid = threadIdx.x;
    int bid = blockIdx.x;                       // 1024 = 8 XCD x 128
    int w = (bid & 7) * 128 + (bid >> 3);
    const int net = w & 1, b0 = (w >> 1) * 128;
    if (tid < 128) qlds[tid] = 0.f;
    const _Float16* Ab = Osum + (long)net * ((long)BATCH * 512) + (long)b0 * 512;
    const _Float16* Bb = R1t + (long)net * 131072;
    const int wid = tid >> 6, lane = tid & 63;
    const int lm = lane & 15, lq = lane >> 4;
    const int wr = (wid >> 2) * 64, wc = (wid & 3) * 64;
    const int xv = lm & 7;
    const int srow = tid >> 3, schk = tid & 7;

    auto stage = [&](int s, int buf) {
        int ko = s * 64;
#pragma unroll
        for (int g = 0; g < 2; ++g) {
            int row = srow + g * 64, q = schk ^ (row & 7);
            GLL16(Ab + (long)row * 512 + ko + q * 8, &As[buf][0] + g * 4096 + wid * 512);
        }
#pragma unroll
        for (int g = 0; g < 4; ++g) {
            int row = srow + g * 64, q = schk ^ (row & 7);
            GLL16(Bb + (long)row * 512 + ko + q * 8, &Bs[buf][0] + g * 4096 + wid * 512);
        }
    };

    stage(0, 0);
    __syncthreads();

    f32x4 acc[4][4] = {};
    int cur = 0;
    for (int r = 0; r < 8; ++r) {
        if (r < 7) stage(r + 1, cur ^ 1);
        const _Float16* ab = &As[cur][0];
        const _Float16* bb = &Bs[cur][0];
#pragma unroll
        for (int ks = 0; ks < 2; ++ks) {
            const int off = ((ks * 4 + lq) ^ xv) * 8;
            half8 a[4], b[4];
#pragma unroll
            for (int i = 0; i < 4; ++i) a[i] = *(const half8*)(ab + (wr + i * 16 + lm) * 64 + off);
#pragma unroll
            for (int j = 0; j < 4; ++j) b[j] = *(const half8*)(bb + (wc + j * 16 + lm) * 64 + off);
#pragma unroll
            for (int i = 0; i < 4; ++i)
#pragma unroll
                for (int j = 0; j < 4; ++j)
                    acc[i][j] = __builtin_amdgcn_mfma_f32_16x16x32_f16(a[i], b[j], acc[i][j], 0, 0, 0);
        }
        __syncthreads();
        cur ^= 1;
    }
    const float* w2 = net ? r2w2 : r1w2;
    const float* rb = rbias + net * 256;
    float w2v[4], bv[4];
#pragma unroll
    for (int j = 0; j < 4; ++j) {
        int col = wc + j * 16 + lm;
        w2v[j] = w2[col];
        bv[j] = rb[col];
    }
    f32x4 qp[4] = {};
#pragma unroll
    for (int i = 0; i < 4; ++i)
#pragma unroll
        for (int j = 0; j < 4; ++j)
#pragma unroll
            for (int rg = 0; rg < 4; ++rg) {
                float v = acc[i][j][rg] + bv[j];
                v = v > 0.f ? v : 0.f;
                qp[i][rg] += v * w2v[j];
            }
#pragma unroll
    for (int d = 1; d < 16; d <<= 1)
#pragma unroll
        for (int i = 0; i < 4; ++i)
#pragma unroll
            for (int rg = 0; rg < 4; ++rg)
                qp[i][rg] += __shfl_xor(qp[i][rg], d, 64);
    if ((lane & 15) == 0) {
#pragma unroll
        for (int i = 0; i < 4; ++i)
#pragma unroll
            for (int rg = 0; rg < 4; ++rg)
                atomicAdd(&qlds[wr + i * 16 + lq * 4 + rg], qp[i][rg]);
    }
    __syncthreads();
    if (tid < 128)
        out[(long)net * BATCH + b0 + tid] = qlds[tid] + (net ? r2b2[0] : r1b2[0]);
}

extern "C" void kernel_launch(void* const* d_in, const int* in_sizes, int n_in,
                              void* d_out, int out_size, void* d_ws, size_t ws_size,
                              hipStream_t stream) {
    const float* obs  = (const float*)d_in[0];
    const float* act  = (const float*)d_in[1];
    const float* nodes= (const float*)d_in[2];
    const float* p1w1 = (const float*)d_in[3];  const float* p1b1 = (const float*)d_in[4];
    const float* p1w2 = (const float*)d_in[5];  const float* p1b2 = (const float*)d_in[6];
    const float* p2w1 = (const float*)d_in[7];  const float* p2b1 = (const float*)d_in[8];
    const float* p2w2 = (const float*)d_in[9];  const float* p2b2 = (const float*)d_in[10];
    const float* r1w1 = (const float*)d_in[11]; const float* r1b1 = (const float*)d_in[12];
    const float* r1w2 = (const float*)d_in[13]; const float* r1b2 = (const float*)d_in[14];
    const float* r2w1 = (const float*)d_in[15]; const float* r2b1 = (const float*)d_in[16];
    const float* r2w2 = (const float*)d_in[17]; const float* r2b2 = (const float*)d_in[18];

    // workspace layout (bytes, 16B aligned)
    const size_t oW1t  = 0;           // 512*160*2     = 163,840
    const size_t oW2t  = 163840;      // 2*512*256*2   = 524,288
    const size_t oR1t  = 688128;      // 2*256*512*2   = 524,288
    const size_t oB1   = 1212416;     // 512*4 = 2,048
    const size_t oB2   = 1214464;     // 2*512*4 = 4,096
    const size_t oRB   = 1218560;     // 2*256*4 = 2,048
    const size_t oXO   = 1220608;     // max(Xh 62,914,560 ; Osum 134,217,728) aliased in time
    const size_t oH    = 135438336;   // H 201,326,592
    const size_t need  = 336764928;
    if (ws_size < need) return;

    char* ws = (char*)d_ws;
    _Float16* W1t  = (_Float16*)(ws + oW1t);
    _Float16* W2t  = (_Float16*)(ws + oW2t);
    _Float16* R1t  = (_Float16*)(ws + oR1t);
    float*    b1cat= (float*)(ws + oB1);
    float*    b2cat= (float*)(ws + oB2);
    float*    rbias= (float*)(ws + oRB);
    _Float16* Xh   = (_Float16*)(ws + oXO);
    _Float16* Osum = (_Float16*)(ws + oXO);  // alias: Xh dead after gemm1
    _Float16* H    = (_Float16*)(ws + oH);
    float* out = (float*)d_out;

    prep_kernel<<<2376, 256, 0, stream>>>(p1w1, p2w1, p1w2, p2w2, r1w1, r2w1,
                                          p1b1, p2b1, p1b2, p2b2, r1b1, r2b1,
                                          W1t, W2t, R1t, b1cat, b2cat, rbias);
    build_x<<<15360, 256, 0, stream>>>(obs, act, nodes, Xh);
    gemm1<<<6144, 256, 0, stream>>>(Xh, W1t, b1cat, H);
    gemm_sum_flat<<<8192, 256, 0, stream>>>(H, W2t, b2cat, Osum);
    gemm3q<<<1024, 512, 0, stream>>>(Osum, R1t, rbias, r1w2, r2w2, r1b2, r2b2, out);
}

// Round 11
// 340.360 us; speedup vs baseline: 1.6882x; 1.6882x over previous
//
#include <hip/hip_runtime.h>
#include <hip/hip_fp16.h>

typedef _Float16 half8 __attribute__((ext_vector_type(8)));
typedef float f32x4 __attribute__((ext_vector_type(4)));

#define BATCH 65536
#define M1 196608   // 3*BATCH
#define K1 160      // X cols permuted: [nodes(128)|act(4)|body(10)|obj(15)|pad(3)]

// global -> LDS direct, 16B per lane, dest = wave-uniform base + lane*16
#define GLL16(g, l) __builtin_amdgcn_global_load_lds( \
    (const __attribute__((address_space(1))) unsigned int*)(const void*)(g), \
    (__attribute__((address_space(3))) unsigned int*)(void*)(l), 16, 0, 0)

#define SBAR() do { __builtin_amdgcn_s_barrier(); __builtin_amdgcn_sched_barrier(0); } while (0)

// ---------------- prep: weights -> fp16 n-major k-contig (permuted/padded), merged biases ----------------
// W1t[512][160], W2t[2][512][256], R1t[2][256][512]
__global__ void prep_kernel(const float* __restrict__ p1w1, const float* __restrict__ p2w1,
                            const float* __restrict__ p1w2, const float* __restrict__ p2w2,
                            const float* __restrict__ r1w1, const float* __restrict__ r2w1,
                            const float* __restrict__ p1b1, const float* __restrict__ p2b1,
                            const float* __restrict__ p1b2, const float* __restrict__ p2b2,
                            const float* __restrict__ rb1a, const float* __restrict__ rb1b,
                            _Float16* __restrict__ W1t, _Float16* __restrict__ W2t,
                            _Float16* __restrict__ R1t, float* __restrict__ b1cat,
                            float* __restrict__ b2cat, float* __restrict__ rbias) {
    int e = blockIdx.x * 256 + threadIdx.x;
    if (e < 81920) {  // W1t[512][160]
        int n = e / 160, c = e % 160;
        int k = (c < 128) ? (29 + c) : (c - 128);   // col order: nodes | act,body,obj | pad
        float v = 0.f;
        if (c < 157) v = (n < 256) ? p1w1[k * 256 + n] : p2w1[k * 256 + (n - 256)];
        W1t[e] = (_Float16)v;
        return;
    }
    e -= 81920;
    if (e < 262144) {  // W2t[2][512][256]
        int net = e >> 17, rr = e & 131071;
        int n = rr >> 8, k = rr & 255;
        const float* w = net ? p2w2 : p1w2;
        W2t[(size_t)net * 131072 + rr] = (n < 471) ? (_Float16)w[k * 471 + n] : (_Float16)0.f;
        return;
    }
    e -= 262144;
    if (e < 262144) {  // R1t[2][256][512]
        int net = e >> 17, rr = e & 131071;
        int n = rr >> 9, k = rr & 511;
        const float* w = net ? r2w1 : r1w1;
        R1t[(size_t)net * 131072 + rr] = (k < 471) ? (_Float16)w[k * 256 + n] : (_Float16)0.f;
        return;
    }
    e -= 262144;
    if (e < 512) { b1cat[e] = (e < 256) ? p1b1[e] : p2b1[e - 256]; return; }
    e -= 512;
    if (e < 1024) {
        int net = e >> 9, n = e & 511;
        b2cat[e] = (n < 471) ? (net ? p2b2 : p1b2)[n] : 0.f;
        return;
    }
    e -= 1024;
    if (e < 512) {
        int net = e >> 8, n = e & 255;
        rbias[e] = (net ? rb1b : rb1a)[n];
    }
}

// ---------------- build X (3B x 160) fp16, permuted cols: [nodes|act|body|obj|pad] ----------------
__global__ void build_x(const float* __restrict__ obs, const float* __restrict__ act,
                        const float* __restrict__ nodes, _Float16* __restrict__ Xh) {
    long idx = (long)blockIdx.x * 256 + threadIdx.x;   // one 16B chunk each; 196608*20 total
    int ch = (int)(idx % 20);
    long r = idx / 20;
    int o = (int)(r >> 16), b = (int)(r & 65535);
    half8 v;
    if (ch < 16) {
        const float* s = nodes + r * 128 + ch * 8;
#pragma unroll
        for (int j = 0; j < 8; ++j) v[j] = (_Float16)s[j];
    } else {
#pragma unroll
        for (int j = 0; j < 8; ++j) {
            int lc = ch * 8 + j - 128;
            float f = 0.f;
            if (lc < 4)       f = act[b * 4 + lc];
            else if (lc < 14) f = obs[b * 55 + (lc - 4)];
            else if (lc < 29) f = obs[b * 55 + 10 + o * 15 + (lc - 14)];
            v[j] = (_Float16)f;
        }
    }
    *(half8*)(Xh + r * K1 + ch * 8) = v;
}

// ---------------- gemm1: H[net][3B][256] = relu(X @ W1 + b1), K=160, BK=32 (5 rounds) ----------------
// 4 waves 64x64, LDS 32 KB, 2-phase dbuf (R9-run proven)
__global__ __launch_bounds__(256) void gemm1(const _Float16* __restrict__ Xh,
                                             const _Float16* __restrict__ W1t,
                                             const float* __restrict__ b1cat,
                                             _Float16* __restrict__ H) {
    __shared__ _Float16 As[2][4096];    // 128 x 32
    __shared__ _Float16 Bs[2][4096];
    const int tid = threadIdx.x;
    int bid = blockIdx.x;                       // 6144 = 8 XCD x 768, n fastest (4 siblings share A)
    int w = (bid & 7) * 768 + (bid >> 3);
    const int m0 = (w >> 2) * 128, n0 = (w & 3) * 128;
    const _Float16* Ab = Xh + (long)m0 * K1;
    const _Float16* Bb = W1t + (long)n0 * K1;
    const int wid = tid >> 6, lane = tid & 63;
    const int lm = lane & 15, lq = lane >> 4;
    const int wr = (wid >> 1) * 64, wc = (wid & 1) * 64;

    auto stage = [&](int s, int buf) {          // BK=32: 2+2 GLL16/thread; dest = c*8 halves
        int ko = s * 32;
#pragma unroll
        for (int t = 0; t < 2; ++t) {
            int c = t * 256 + tid, row = c >> 2, chk = c & 3;
            int q = chk ^ ((row >> 1) & 3);
            GLL16(Ab + (long)row * K1 + ko + q * 8, &As[buf][0] + t * 2048 + wid * 512);
            GLL16(Bb + (long)row * K1 + ko + q * 8, &Bs[buf][0] + t * 2048 + wid * 512);
        }
    };

    stage(0, 0);
    __syncthreads();

    const int cc = (lq ^ ((lm >> 1) & 3)) * 8;
    f32x4 acc[4][4] = {};
    int cur = 0;
#pragma unroll
    for (int r = 0; r < 5; ++r) {
        if (r < 4) stage(r + 1, cur ^ 1);
        const _Float16* ab = &As[cur][0];
        const _Float16* bb = &Bs[cur][0];
        half8 a[4], b[4];
#pragma unroll
        for (int i = 0; i < 4; ++i) a[i] = *(const half8*)(ab + (wr + i * 16 + lm) * 32 + cc);
#pragma unroll
        for (int j = 0; j < 4; ++j) b[j] = *(const half8*)(bb + (wc + j * 16 + lm) * 32 + cc);
#pragma unroll
        for (int i = 0; i < 4; ++i)
#pragma unroll
            for (int j = 0; j < 4; ++j)
                acc[i][j] = __builtin_amdgcn_mfma_f32_16x16x32_f16(a[i], b[j], acc[i][j], 0, 0, 0);
        __syncthreads();
        cur ^= 1;
    }
#pragma unroll
    for (int j = 0; j < 4; ++j) {
        int n = n0 + wc + j * 16 + lm;
        int net = n >> 8, ncol = n & 255;
        float bi = b1cat[n];
        _Float16* hp = H + (long)net * ((long)M1 * 256) + ncol;
#pragma unroll
        for (int i = 0; i < 4; ++i) {
            int mrow = m0 + wr + i * 16 + lq * 4;
#pragma unroll
            for (int rg = 0; rg < 4; ++rg) {
                float v = acc[i][j][rg] + bi;
                v = v > 0.f ? v : 0.f;
                hp[(long)(mrow + rg) * 256] = (_Float16)v;
            }
        }
    }
}

// ---------------- gemm2: Osum[net][B][512] = sum_o relu(H[net][o] @ W2^T + b2) ----------------
// R2-proven geometry (512 thr, 8 waves 64x32, BK=32, BN=128) + 3-buf counted-vmcnt ring.
// LDS 48 KB -> 3 blocks/CU. stage = 2 GLL16/thread; steady wait vmcnt(2), FINAL round vmcnt(0).
__global__ __launch_bounds__(512) void gemm_sum(const _Float16* __restrict__ H,
                                                const _Float16* __restrict__ W2t,
                                                const float* __restrict__ b2cat,
                                                _Float16* __restrict__ Osum) {
    __shared__ _Float16 As[3][4096];    // 128 x 32
    __shared__ _Float16 Bs[3][4096];    // 128 x 32
    const int tid = threadIdx.x;
    int bid = blockIdx.x;                       // 4096 = 8 XCD x 512; n fastest, then net, then m
    int w = (bid & 7) * 512 + (bid >> 3);
    const int n0 = (w & 3) * 128, net = (w >> 2) & 1, b0 = (w >> 3) * 128;
    const _Float16* Ab = H + (long)net * ((long)M1 * 256) + (long)b0 * 256;
    const _Float16* Bb = W2t + (long)net * 131072 + (long)n0 * 256;
    const int wid = tid >> 6, lane = tid & 63;
    const int lm = lane & 15, lq = lane >> 4;
    const int wr = (wid >> 2) * 64, wc = (wid & 3) * 32;
    const int srow = tid >> 2, schk = tid & 3;          // 512 thr cover 128 rows x 4 chunks
    const int sq = schk ^ ((srow >> 1) & 3);

    float bi[2];
#pragma unroll
    for (int j = 0; j < 2; ++j) bi[j] = b2cat[net * 512 + n0 + wc + j * 16 + lm];

    auto stage = [&](int g) {                   // 1 A + 1 B GLL16 per thread
        int obj = g >> 3, ko = (g & 7) * 32;
        GLL16(Ab + ((long)obj * BATCH + srow) * 256 + ko + sq * 8, &As[g % 3][0] + wid * 512);
        GLL16(Bb + (long)srow * 256 + ko + sq * 8, &Bs[g % 3][0] + wid * 512);
    };

    stage(0); stage(1);

    const int cc = (lq ^ ((lm >> 1) & 3)) * 8;
    f32x4 acc[4][2] = {};
    f32x4 sum[4][2] = {};
    for (int r = 0; r < 24; ++r) {
        // in flight: stage(r)[2] + stage(r+1)[2] -> vmcnt(2) retires stage(r).
        // FINAL round: only stage(23)[2] in flight -> must drain to 0 (R6 tail lesson).
        if (r < 23) { asm volatile("s_waitcnt vmcnt(2) lgkmcnt(0)" ::: "memory"); }
        else        { asm volatile("s_waitcnt vmcnt(0) lgkmcnt(0)" ::: "memory"); }
        SBAR();
        if (r + 2 < 24) stage(r + 2);
        const _Float16* ab = &As[r % 3][0];
        const _Float16* bb = &Bs[r % 3][0];
        half8 a[4], b[2];
#pragma unroll
        for (int i = 0; i < 4; ++i) a[i] = *(const half8*)(ab + (wr + i * 16 + lm) * 32 + cc);
#pragma unroll
        for (int j = 0; j < 2; ++j) b[j] = *(const half8*)(bb + (wc + j * 16 + lm) * 32 + cc);
#pragma unroll
        for (int i = 0; i < 4; ++i)
#pragma unroll
            for (int j = 0; j < 2; ++j)
                acc[i][j] = __builtin_amdgcn_mfma_f32_16x16x32_f16(a[i], b[j], acc[i][j], 0, 0, 0);
        if ((r & 7) == 7) {  // object boundary: bias + relu + accumulate, reset
#pragma unroll
            for (int i = 0; i < 4; ++i)
#pragma unroll
                for (int j = 0; j < 2; ++j) {
#pragma unroll
                    for (int rg = 0; rg < 4; ++rg) {
                        float v = acc[i][j][rg] + bi[j];
                        sum[i][j][rg] += (v > 0.f ? v : 0.f);
                    }
                    acc[i][j] = f32x4{0.f, 0.f, 0.f, 0.f};
                }
        }
    }
    _Float16* op = Osum + (long)net * ((long)BATCH * 512);
#pragma unroll
    for (int j = 0; j < 2; ++j) {
        int n = n0 + wc + j * 16 + lm;
#pragma unroll
        for (int i = 0; i < 4; ++i) {
            int mrow = b0 + wr + i * 16 + lq * 4;
#pragma unroll
            for (int rg = 0; rg < 4; ++rg)
                op[(long)(mrow + rg) * 512 + n] = (_Float16)sum[i][j][rg];
        }
    }
}

// ---------------- gemm3+qdot fused: q = relu(Osum @ R1 + rb1) . w2 + b2 ----------------
// BM=128, BN=256 (full per net), BK=32, 16 rounds, 8 waves 64x64,
// 3-buf counted-vmcnt ring (72 KB LDS -> 2 blocks/CU). stage = 3 GLL16/thread -> vmcnt(3).
__global__ __launch_bounds__(512) void gemm3q(const _Float16* __restrict__ Osum,
                                              const _Float16* __restrict__ R1t,
                                              const float* __restrict__ rbias,
                                              const float* __restrict__ r1w2,
                                              const float* __restrict__ r2w2,
                                              const float* __restrict__ r1b2,
                                              const float* __restrict__ r2b2,
                                              float* __restrict__ out) {
    __shared__ _Float16 As[3][4096];    // 128 x 32
    __shared__ _Float16 Bs[3][8192];    // 256 x 32
    __shared__ float qlds[128];
    const int tid = threadIdx.x;
    int bid = blockIdx.x;                       // 1024 = 8 XCD x 128
    int w = (bid & 7) * 128 + (bid >> 3);
    const int net = w & 1, b0 = (w >> 1) * 128;
    if (tid < 128) qlds[tid] = 0.f;
    const _Float16* Ab = Osum + (long)net * ((long)BATCH * 512) + (long)b0 * 512;
    const _Float16* Bb = R1t + (long)net * 131072;
    const int wid = tid >> 6, lane = tid & 63;
    const int lm = lane & 15, lq = lane >> 4;
    const int wr = (wid >> 2) * 64, wc = (wid & 3) * 64;
    const int srow = tid >> 2, schk = tid & 3;
    const int sq = schk ^ ((srow >> 1) & 3);

    auto stage = [&](int g) {                   // A: 1 call (128 rows), B: 2 calls (256 rows)
        int ko = g * 32;
        GLL16(Ab + (long)srow * 512 + ko + sq * 8, &As[g % 3][0] + wid * 512);
#pragma unroll
        for (int t = 0; t < 2; ++t) {
            int row = srow + t * 128;
            int q = schk ^ ((row >> 1) & 3);
            GLL16(Bb + (long)row * 512 + ko + q * 8, &Bs[g % 3][0] + t * 4096 + wid * 512);
        }
    };

    stage(0); stage(1);

    const int cc = (lq ^ ((lm >> 1) & 3)) * 8;
    f32x4 acc[4][4] = {};
    for (int r = 0; r < 16; ++r) {
        if (r < 15) { asm volatile("s_waitcnt vmcnt(3) lgkmcnt(0)" ::: "memory"); }
        else        { asm volatile("s_waitcnt vmcnt(0) lgkmcnt(0)" ::: "memory"); }
        SBAR();
        if (r + 2 < 16) stage(r + 2);
        const _Float16* ab = &As[r % 3][0];
        const _Float16* bb = &Bs[r % 3][0];
        half8 a[4], b[4];
#pragma unroll
        for (int i = 0; i < 4; ++i) a[i] = *(const half8*)(ab + (wr + i * 16 + lm) * 32 + cc);
#pragma unroll
        for (int j = 0; j < 4; ++j) b[j] = *(const half8*)(bb + (wc + j * 16 + lm) * 32 + cc);
#pragma unroll
        for (int i = 0; i < 4; ++i)
#pragma unroll
            for (int j = 0; j < 4; ++j)
                acc[i][j] = __builtin_amdgcn_mfma_f32_16x16x32_f16(a[i], b[j], acc[i][j], 0, 0, 0);
    }
    const float* w2 = net ? r2w2 : r1w2;
    const float* rb = rbias + net * 256;
    float w2v[4], bv[4];
#pragma unroll
    for (int j = 0; j < 4; ++j) {
        int col = wc + j * 16 + lm;
        w2v[j] = w2[col];
        bv[j] = rb[col];
    }
    f32x4 qp[4] = {};
#pragma unroll
    for (int i = 0; i < 4; ++i)
#pragma unroll
        for (int j = 0; j < 4; ++j)
#pragma unroll
            for (int rg = 0; rg < 4; ++rg) {
                float v = acc[i][j][rg] + bv[j];
                v = v > 0.f ? v : 0.f;
                qp[i][rg] += v * w2v[j];
            }
#pragma unroll
    for (int d = 1; d < 16; d <<= 1)
#pragma unroll
        for (int i = 0; i < 4; ++i)
#pragma unroll
            for (int rg = 0; rg < 4; ++rg)
                qp[i][rg] += __shfl_xor(qp[i][rg], d, 64);
    if ((lane & 15) == 0) {
#pragma unroll
        for (int i = 0; i < 4; ++i)
#pragma unroll
            for (int rg = 0; rg < 4; ++rg)
                atomicAdd(&qlds[wr + i * 16 + lq * 4 + rg], qp[i][rg]);
    }
    __syncthreads();
    if (tid < 128)
        out[(long)net * BATCH + b0 + tid] = qlds[tid] + (net ? r2b2[0] : r1b2[0]);
}

extern "C" void kernel_launch(void* const* d_in, const int* in_sizes, int n_in,
                              void* d_out, int out_size, void* d_ws, size_t ws_size,
                              hipStream_t stream) {
    const float* obs  = (const float*)d_in[0];
    const float* act  = (const float*)d_in[1];
    const float* nodes= (const float*)d_in[2];
    const float* p1w1 = (const float*)d_in[3];  const float* p1b1 = (const float*)d_in[4];
    const float* p1w2 = (const float*)d_in[5];  const float* p1b2 = (const float*)d_in[6];
    const float* p2w1 = (const float*)d_in[7];  const float* p2b1 = (const float*)d_in[8];
    const float* p2w2 = (const float*)d_in[9];  const float* p2b2 = (const float*)d_in[10];
    const float* r1w1 = (const float*)d_in[11]; const float* r1b1 = (const float*)d_in[12];
    const float* r1w2 = (const float*)d_in[13]; const float* r1b2 = (const float*)d_in[14];
    const float* r2w1 = (const float*)d_in[15]; const float* r2b1 = (const float*)d_in[16];
    const float* r2w2 = (const float*)d_in[17]; const float* r2b2 = (const float*)d_in[18];

    // workspace layout (bytes, 16B aligned)
    const size_t oW1t  = 0;           // 512*160*2     = 163,840
    const size_t oW2t  = 163840;      // 2*512*256*2   = 524,288
    const size_t oR1t  = 688128;      // 2*256*512*2   = 524,288
    const size_t oB1   = 1212416;     // 512*4 = 2,048
    const size_t oB2   = 1214464;     // 2*512*4 = 4,096
    const size_t oRB   = 1218560;     // 2*256*4 = 2,048
    const size_t oXO   = 1220608;     // max(Xh 62,914,560 ; Osum 134,217,728) aliased in time
    const size_t oH    = 135438336;   // H 201,326,592
    const size_t need  = 336764928;
    if (ws_size < need) return;

    char* ws = (char*)d_ws;
    _Float16* W1t  = (_Float16*)(ws + oW1t);
    _Float16* W2t  = (_Float16*)(ws + oW2t);
    _Float16* R1t  = (_Float16*)(ws + oR1t);
    float*    b1cat= (float*)(ws + oB1);
    float*    b2cat= (float*)(ws + oB2);
    float*    rbias= (float*)(ws + oRB);
    _Float16* Xh   = (_Float16*)(ws + oXO);
    _Float16* Osum = (_Float16*)(ws + oXO);  // alias: Xh dead after gemm1
    _Float16* H    = (_Float16*)(ws + oH);
    float* out = (float*)d_out;

    prep_kernel<<<2376, 256, 0, stream>>>(p1w1, p2w1, p1w2, p2w2, r1w1, r2w1,
                                          p1b1, p2b1, p1b2, p2b2, r1b1, r2b1,
                                          W1t, W2t, R1t, b1cat, b2cat, rbias);
    build_x<<<15360, 256, 0, stream>>>(obs, act, nodes, Xh);
    gemm1<<<6144, 256, 0, stream>>>(Xh, W1t, b1cat, H);
    gemm_sum<<<4096, 512, 0, stream>>>(H, W2t, b2cat, Osum);
    gemm3q<<<1024, 512, 0, stream>>>(Osum, R1t, rbias, r1w2, r2w2, r1b2, r2b2, out);
}